// Round 6
// baseline (704.032 us; speedup 1.0000x reference)
//
#include <hip/hip_runtime.h>

// VQ-VAE vector-quantize, fused: distances + argmin + gather + loss.
// x: [65536, 256] fp32, dict: [256, 1024] fp32.
// out: q_ste [65536*256] fp32, then loss scalar at out[65536*256].
//
// NUMERICS (bit-exact vs np reference, verified absmax 0.0 R2-R10 — DO NOT CHANGE):
//  - row norm ||f||^2: np pairwise tree (two INDEPENDENT 128-halves, each an
//    8-accumulator r8[e&7] chain, unfused squares, fixed combine tree,
//    result = half0_tree + half1_tree; 0+sq == sq so zero-init is exact)
//  - enorm ||e||^2: sequential d ascending, unfused square then plain add
//  - dist = fl( fl(A + B) - 2*s ), argmin first-index on exact ties
//  - STE out = fl(x + fl(q - x)); loss on pure q, (1+BETA)/(N*D) scale
//
// PERF (R10 -> R11): R10 (dict via global) regressed -> dict returns to LDS
// (R9 loop). R8+R10 localize the ~36% stall to the per-step serialized
// x-stage: load -> vmcnt wait -> ds_write with ZERO issue-to-wait distance,
// HBM-latency-exposed every step (FETCH 169MB = x is HBM-served). R11 = T14
// minimal: loads pinned at step top (sched_barrier), writes sunk below dd 0..3
// (~1024 cyc cover), pv live across only 4 dd iters (+8 VGPR worst case —
// R6's spill came from bundling this with norm-piggyback regs).
// Also: prep+rnorm merged into one vq_aux dispatch; epilogue unroll 8.

#define NROWS 65536
#define DDIM  256
#define KC    1024
#define BM    128            // rows per block
#define BC    256            // codes per ct tile
#define DC    16             // d-chunk per pipeline step
#define NDC   16             // DDIM/DC
#define NCT   4              // KC/BC
#define NSTEP 64             // NCT*NDC
#define FXW   128            // 128 rows, pitch 4 packed (reads conflict-free)

#define GLOAD_LDS16(gp, lp) __builtin_amdgcn_global_load_lds( \
    (const __attribute__((address_space(1))) void*)(gp),      \
    (__attribute__((address_space(3))) void*)(lp), 16, 0, 0)

// x chunk [128 rows][16 d] prefetch: global loads issued at step top, LDS
// transpose-write sunk below dd 0..3 (pv live across 4 dd iters only).
#define STAGE_FX_LOAD(dc_) do {                                                 \
    const int r0_ = tid >> 2, c0_ = tid & 3;                                    \
    pv0 = *(const float4*)&x[(size_t)(rowbase + r0_) * DDIM + (dc_) * DC + c0_ * 4];      \
    pv1 = *(const float4*)&x[(size_t)(rowbase + 64 + r0_) * DDIM + (dc_) * DC + c0_ * 4]; \
} while (0)

#define STAGE_FX_WRITE(dstbuf) do {                                             \
    const int r0_ = tid >> 2, c0_ = tid & 3;                                    \
    float* b0_ = (dstbuf) + (c0_ * 4) * FXW + r0_;                              \
    b0_[0 * FXW] = pv0.x; b0_[1 * FXW] = pv0.y;                                 \
    b0_[2 * FXW] = pv0.z; b0_[3 * FXW] = pv0.w;                                 \
    float* b1_ = b0_ + 64;               /* +64 rows */                         \
    b1_[0 * FXW] = pv1.x; b1_[1 * FXW] = pv1.y;                                 \
    b1_[2 * FXW] = pv1.z; b1_[3 * FXW] = pv1.w;                                 \
} while (0)

// dict tile [16 d][256 codes] via async DMA: lds dest = uniform + lane*16.
#define STAGE_DICT(pbuf, ct_, dc_) do {                                         \
    _Pragma("unroll")                                                           \
    for (int i_ = 0; i_ < 4; ++i_) {                                            \
        int flat_ = i_ * 256 + tid;                                             \
        int dd_ = flat_ >> 6;            /* wave-uniform */                     \
        int l4_ = (flat_ & 63) * 4;      /* lane*4 floats = lane*16 B */        \
        GLOAD_LDS16(&dict[(size_t)((dc_) * DC + dd_) * KC + (ct_) * BC + l4_],  \
                    (pbuf) + dd_ * BC + l4_);                                   \
    }                                                                           \
} while (0)

// Inner-product micro-tile: 8 rows x 16 codes, one d-slice.
#define DD_BODY(dd) do {                                                        \
    const float4 f0 = *(const float4*)&fXb[p][(dd) * FXW + ty * 8];             \
    const float4 f1 = *(const float4*)&fXb[p][(dd) * FXW + ty * 8 + 4];         \
    const float4 e0 = *(const float4*)&dTs[p][(dd) * BC + tx * 4];              \
    const float4 e1 = *(const float4*)&dTs[p][(dd) * BC + 64 + tx * 4];         \
    const float4 e2 = *(const float4*)&dTs[p][(dd) * BC + 128 + tx * 4];        \
    const float4 e3 = *(const float4*)&dTs[p][(dd) * BC + 192 + tx * 4];        \
    const float fr[8]  = {f0.x, f0.y, f0.z, f0.w, f1.x, f1.y, f1.z, f1.w};      \
    const float ec[16] = {e0.x, e0.y, e0.z, e0.w, e1.x, e1.y, e1.z, e1.w,       \
                          e2.x, e2.y, e2.z, e2.w, e3.x, e3.y, e3.z, e3.w};      \
    _Pragma("unroll")                                                           \
    for (int r = 0; r < 8; ++r)                                                 \
        _Pragma("unroll")                                                       \
        for (int j = 0; j < 16; ++j)                                            \
            acc[r][j] = fmaf(fr[r], ec[j], acc[r][j]);                          \
} while (0)

// Merged pre-pass. Blocks 0..3: codebook transpose + column norms (np order:
// rounded square then plain add, d strictly ascending) + loss zero-init.
// Blocks 4..515: row norms, 2 threads/row (independent 128-halves of the np
// chain, each the verified 8-acc r8 chain; __shfl_down(1) combine).
__global__ __launch_bounds__(256) void vq_aux(const float* __restrict__ x,
                                              const float* __restrict__ dict,
                                              float* __restrict__ enorm,
                                              float* __restrict__ dictT,
                                              float* __restrict__ rnorm,
                                              float* __restrict__ loss) {
#pragma clang fp contract(off)
    const int tid = threadIdx.x;
    if (blockIdx.x < 4) {
        const int k = blockIdx.x * 256 + tid;
        if (k == 0) *loss = 0.f;         // aux completes before vq_main (stream order)
        float s = 0.f;
        #pragma unroll 8
        for (int d = 0; d < DDIM; ++d) { // d strictly ascending
            float v = dict[(size_t)d * KC + k];
            float sq = v * v;            // rounded square (np temp array)
            s = s + sq;                  // plain add, NOT fma (sequential chain)
            dictT[(size_t)k * DDIM + d] = v;
        }
        enorm[k] = s;
    } else {
        int gt   = (blockIdx.x - 4) * 256 + tid;   // 2*NROWS threads
        int row  = gt >> 1;
        int half = gt & 1;
        const float* xr = x + (size_t)row * DDIM + half * 128;
        float r8[8] = {0.f, 0.f, 0.f, 0.f, 0.f, 0.f, 0.f, 0.f};
        #pragma unroll 8
        for (int c = 0; c < 32; ++c) {   // local e = 4c..4c+3 ; e&7 == (c&1)*4+k
            float4 v = *(const float4*)&xr[c * 4];
            int b = (c & 1) * 4;
            float s0 = v.x * v.x; r8[b + 0] = r8[b + 0] + s0;
            float s1 = v.y * v.y; r8[b + 1] = r8[b + 1] + s1;
            float s2 = v.z * v.z; r8[b + 2] = r8[b + 2] + s2;
            float s3 = v.w * v.w; r8[b + 3] = r8[b + 3] + s3;
        }
        float h = ((r8[0] + r8[1]) + (r8[2] + r8[3]))
                + ((r8[4] + r8[5]) + (r8[6] + r8[7]));
        float ho = __shfl_down(h, 1, 64);    // odd lane's half-1 tree
        if (half == 0) rnorm[row] = h + ho;  // fl(half0 + half1) — verified chain
    }
}

__global__ __launch_bounds__(256, 2) void vq_main(const float* __restrict__ x,
                                                  const float* __restrict__ dict,
                                                  const float* __restrict__ enorm,
                                                  const float* __restrict__ dictT,
                                                  const float* __restrict__ rnorm,
                                                  float* __restrict__ out,
                                                  float* __restrict__ loss) {
    __shared__ float fXb[2][DC * FXW];   // 8 KB each
    __shared__ float dTs[2][DC * BC];    // 16 KB each  -> total 48 KB, 2 blk/CU

    const int tid = threadIdx.x;
    const int tx  = tid & 15;            // 16 code-groups x 16 codes = 256
    const int ty  = tid >> 4;            // 16 row-groups  x  8 rows  = 128
    const int rowbase = blockIdx.x * BM;

    // Row norms from vq_aux (broadcast loads: 16 lanes share ty). row = 8*ty+r.
    float Arow[8];
    #pragma unroll
    for (int r = 0; r < 8; ++r) Arow[r] = rnorm[rowbase + ty * 8 + r];

    float minv[8];
    int   mini[8];
    #pragma unroll
    for (int r = 0; r < 8; ++r) { minv[r] = 3.4e38f; mini[r] = 0; }

    // ---- Prologue: dict tile (0,0) DMA + x chunk 0, one barrier drains both.
    STAGE_DICT(&dTs[0][0], 0, 0);
    {
        float4 pv0, pv1;
        STAGE_FX_LOAD(0);
        STAGE_FX_WRITE(&fXb[0][0]);
    }
    __syncthreads();

    float acc[8][16];
    // ---- Main: 64 steps, one barrier each. Per step:
    //   [dict DMA + x loads]  (pinned at top by sched_barrier)
    //   dd 0..3               (~1024 cyc of FMA covering the x-load latency)
    //   [x LDS writes]        (vmcnt wait lands here, latency already hidden)
    //   dd 4..15, finalize, barrier.
    #pragma unroll 2                     // compile-time buffer parity
    for (int s = 0; s < NSTEP; ++s) {
        const int p = s & 1;
        float4 pv0, pv1;
        if (s < NSTEP - 1) {
            const int ns = s + 1;
            STAGE_DICT(&dTs[1 - p][0], ns >> 4, ns & 15);  // async, 0 regs
            STAGE_FX_LOAD(ns & 15);                        // issue early
        }
        __builtin_amdgcn_sched_barrier(0);  // pin load issue at step top
        if ((s & 15) == 0) {
            #pragma unroll
            for (int r = 0; r < 8; ++r)
                #pragma unroll
                for (int j = 0; j < 16; ++j) acc[r][j] = 0.f;
        }
        #pragma unroll
        for (int dd = 0; dd < 4; ++dd) DD_BODY(dd);
        __builtin_amdgcn_sched_barrier(0);  // writes stay below dd 0..3
        if (s < NSTEP - 1) STAGE_FX_WRITE(&fXb[1 - p][0]);
        #pragma unroll 4
        for (int dd = 4; dd < DC; ++dd) DD_BODY(dd);
        if ((s & 15) == 15) {
            // dist = fl( fl(A + B) - 2*s ) — np rounding chain (fma of
            // t1 - 2*acc bit-identical: 2*acc exact). Codes ascend with
            // (ct, j) for fixed tx -> strict < keeps FIRST min index.
            const int cbase = (s >> 4) * BC;
            float en[16];
            #pragma unroll
            for (int j = 0; j < 16; ++j)
                en[j] = enorm[cbase + (j >> 2) * 64 + tx * 4 + (j & 3)];
            #pragma unroll
            for (int r = 0; r < 8; ++r)
                #pragma unroll
                for (int j = 0; j < 16; ++j) {
                    int code = cbase + (j >> 2) * 64 + tx * 4 + (j & 3);
                    float t1 = Arow[r] + en[j];
                    float dist = t1 - 2.0f * acc[r][j];
                    if (dist < minv[r]) { minv[r] = dist; mini[r] = code; }
                }
        }
        __syncthreads();
    }

    // Cross-lane argmin over the 16 tx lanes (xor<16 stays in-wave; lane =
    // (ty&3)*16 + tx). Tie -> smaller index (first occurrence).
    #pragma unroll
    for (int m = 1; m < 16; m <<= 1)
        #pragma unroll
        for (int r = 0; r < 8; ++r) {
            float ov = __shfl_xor(minv[r], m, 64);
            int   oi = __shfl_xor(mini[r], m, 64);
            if (ov < minv[r] || (ov == minv[r] && oi < mini[r])) {
                minv[r] = ov; mini[r] = oi;
            }
        }

    int* idx_s = (int*)&dTs[0][0];       // loop-end barrier covers last compute
    if (tx == 0) {
        #pragma unroll
        for (int r = 0; r < 8; ++r) idx_s[ty * 8 + r] = mini[r];
    }
    __syncthreads();

    // Epilogue: gather codebook row (dictT L2-resident), re-read x,
    // emulate STE out = fl(x + fl(q-x)), loss on pure q (before STE).
    // unroll 8 = 8 gathers in flight (latency-bound tail); lsum chain order
    // preserved (sequential adds, no reassociation). Nontemporal stores.
    float lsum = 0.f;
    {
#pragma clang fp contract(off)
        #pragma unroll 8
        for (int i = 0; i < BM; ++i) {
            int k = idx_s[i];
            float qv = dictT[(size_t)k * DDIM + tid];
            float xv = x[(size_t)(rowbase + i) * DDIM + tid];
            float diff = qv - xv;                                 // fl(q - x)
            __builtin_nontemporal_store(xv + diff,
                &out[(size_t)(rowbase + i) * DDIM + tid]);        // fl(x + fl(q-x))
            float d = xv - qv;
            float dsq = d * d;
            lsum = lsum + dsq;
        }
    }
    #pragma unroll
    for (int off = 32; off > 0; off >>= 1)
        lsum += __shfl_down(lsum, off, 64);
    if ((tid & 63) == 0)
        atomicAdd(loss, lsum * (1.25f / 16777216.0f));  // (1+BETA)/(N*D)
}

extern "C" void kernel_launch(void* const* d_in, const int* in_sizes, int n_in,
                              void* d_out, int out_size, void* d_ws, size_t ws_size,
                              hipStream_t stream) {
    (void)in_sizes; (void)n_in; (void)out_size; (void)ws_size;
    const float* x    = (const float*)d_in[0];
    const float* dict = (const float*)d_in[1];
    float* out   = (float*)d_out;
    float* enorm = (float*)d_ws;                 // 1024 floats
    float* dictT = enorm + KC;                   // 1024*256 floats (1 MB)
    float* rnorm = dictT + (size_t)KC * DDIM;    // 65536 floats (256 KB)
    float* loss  = out + (size_t)NROWS * DDIM;   // scalar slot after q

    vq_aux<<<4 + 2 * NROWS / 256, 256, 0, stream>>>(x, dict, enorm, dictT, rnorm, loss);
    vq_main<<<NROWS / BM, 256, 0, stream>>>(x, dict, enorm, dictT, rnorm, out, loss);
}

// Round 7
// 524.008 us; speedup vs baseline: 1.3436x; 1.3436x over previous
//
#include <hip/hip_runtime.h>

// VQ-VAE vector-quantize, fused: distances + argmin + gather + loss.
// x: [65536, 256] fp32, dict: [256, 1024] fp32.
// out: q_ste [65536*256] fp32, then loss scalar at out[65536*256].
//
// NUMERICS (bit-exact vs np reference, verified absmax 0.0 R2-R11 — DO NOT CHANGE):
//  - row norm ||f||^2: np pairwise tree (two INDEPENDENT 128-halves, each an
//    8-accumulator r8[e&7] chain, unfused squares, fixed combine tree,
//    result = half0_tree + half1_tree; 0+sq == sq so zero-init is exact)
//  - enorm ||e||^2: sequential d ascending, unfused square then plain add
//  - dist = fl( fl(A + B) - 2*s ), argmin first-index on exact ties
//  - STE out = fl(x + fl(q - x)); loss on pure q, (1+BETA)/(N*D) scale
//
// PERF (R11 -> R12): R11 re-confirmed T14 spills (WRITE 607MB) — prefetch regs
// can never live across the dd-loop with acc[8][16]=128 VGPRs. Main loop stays
// the proven R9 structure (455us, no spill). This round attacks the ~74us of
// non-main time instead:
//  - rnorm folded into vq_main's PROLOGUE, block-local (own 128 rows, verified
//    two-half chain, 2 thr/row, result to LDS). Kills the rnorm kernel, its
//    64MB global round-trip and one launch gap. Regs are scoped (dead before
//    the main loop -> no spill pressure). Dict tile-0 DMA overlaps it.
//  - vq_prep: 16 blocks x 64 threads (was 4x256 on 4 CUs) -> 4x the CUs for
//    the latency-bound column-norm chains. Same chains, same writes.

#define NROWS 65536
#define DDIM  256
#define KC    1024
#define BM    128            // rows per block
#define BC    256            // codes per ct tile
#define DC    16             // d-chunk per pipeline step
#define NDC   16             // DDIM/DC
#define NCT   4              // KC/BC
#define NSTEP 64             // NCT*NDC
#define FXW   128            // 128 rows, pitch 4 packed (reads conflict-free)

#define GLOAD_LDS16(gp, lp) __builtin_amdgcn_global_load_lds( \
    (const __attribute__((address_space(1))) void*)(gp),      \
    (__attribute__((address_space(3))) void*)(lp), 16, 0, 0)

// x chunk [128 rows][16 d] -> LDS transposed [d][row]. 2 float4/thread,
// regs die immediately (stores right after the vmcnt wait).
#define STAGE_FX(dstbuf, dc_) do {                                              \
    const int r0_ = tid >> 2, c0_ = tid & 3;                                    \
    const float4 v0_ = *(const float4*)&x[(size_t)(rowbase + r0_) * DDIM + (dc_) * DC + c0_ * 4];      \
    const float4 v1_ = *(const float4*)&x[(size_t)(rowbase + 64 + r0_) * DDIM + (dc_) * DC + c0_ * 4]; \
    float* b0_ = (dstbuf) + (c0_ * 4) * FXW + r0_;                              \
    b0_[0 * FXW] = v0_.x; b0_[1 * FXW] = v0_.y;                                 \
    b0_[2 * FXW] = v0_.z; b0_[3 * FXW] = v0_.w;                                 \
    float* b1_ = b0_ + 64;               /* +64 rows */                         \
    b1_[0 * FXW] = v1_.x; b1_[1 * FXW] = v1_.y;                                 \
    b1_[2 * FXW] = v1_.z; b1_[3 * FXW] = v1_.w;                                 \
} while (0)

// dict tile [16 d][256 codes] via async DMA: lds dest = uniform + lane*16.
#define STAGE_DICT(pbuf, ct_, dc_) do {                                         \
    _Pragma("unroll")                                                           \
    for (int i_ = 0; i_ < 4; ++i_) {                                            \
        int flat_ = i_ * 256 + tid;                                             \
        int dd_ = flat_ >> 6;            /* wave-uniform */                     \
        int l4_ = (flat_ & 63) * 4;      /* lane*4 floats = lane*16 B */        \
        GLOAD_LDS16(&dict[(size_t)((dc_) * DC + dd_) * KC + (ct_) * BC + l4_],  \
                    (pbuf) + dd_ * BC + l4_);                                   \
    }                                                                           \
} while (0)

// Pre-kernel: codebook column norms (np order: rounded square then plain add,
// sequential d ascending) + transposed codebook + loss zero-init.
// 16 blocks x 64 threads: one column per thread, coalesced 64-wide loads,
// 16 CUs working the latency-bound chains (was 4).
__global__ __launch_bounds__(64) void vq_prep(const float* __restrict__ dict,
                                              float* __restrict__ enorm,
                                              float* __restrict__ dictT,
                                              float* __restrict__ loss) {
#pragma clang fp contract(off)
    int k = blockIdx.x * 64 + threadIdx.x;
    if (k == 0) *loss = 0.f;   // runs before vq_main (stream order)
    float s = 0.f;
    #pragma unroll 8
    for (int d = 0; d < DDIM; ++d) {
        float v = dict[(size_t)d * KC + k];
        float sq = v * v;          // rounded square (np temp array)
        s = s + sq;                // plain add, NOT fma (chain stays sequential)
        dictT[(size_t)k * DDIM + d] = v;
    }
    enorm[k] = s;
}

__global__ __launch_bounds__(256, 2) void vq_main(const float* __restrict__ x,
                                                  const float* __restrict__ dict,
                                                  const float* __restrict__ enorm,
                                                  const float* __restrict__ dictT,
                                                  float* __restrict__ out,
                                                  float* __restrict__ loss) {
    __shared__ float fXb[2][DC * FXW];   // 8 KB each
    __shared__ float dTs[2][DC * BC];    // 16 KB each
    __shared__ float rnormS[BM];         // 0.5 KB -> total 48.5 KB, 2 blk/CU

    const int tid = threadIdx.x;
    const int tx  = tid & 15;            // 16 code-groups x 16 codes = 256
    const int ty  = tid >> 4;            // 16 row-groups  x  8 rows  = 128
    const int rowbase = blockIdx.x * BM;

    // ---- Prologue. Dict tile (0,0) DMA first (overlaps the rnorm reads).
    STAGE_DICT(&dTs[0][0], 0, 0);

    // Block-local row norms: verified np two-half chain (R9 vq_rnorm body),
    // 2 threads/row over this block's 128 rows. Regs scoped -> dead before
    // the main loop (no spill pressure).
    {
#pragma clang fp contract(off)
        const int row  = tid >> 1;
        const int half = tid & 1;
        const float* xr = x + (size_t)(rowbase + row) * DDIM + half * 128;
        float r8[8] = {0.f, 0.f, 0.f, 0.f, 0.f, 0.f, 0.f, 0.f};
        #pragma unroll 8
        for (int c = 0; c < 32; ++c) {   // local e = 4c..4c+3 ; e&7 == (c&1)*4+k
            float4 v = *(const float4*)&xr[c * 4];
            int b = (c & 1) * 4;
            float s0 = v.x * v.x; r8[b + 0] = r8[b + 0] + s0;
            float s1 = v.y * v.y; r8[b + 1] = r8[b + 1] + s1;
            float s2 = v.z * v.z; r8[b + 2] = r8[b + 2] + s2;
            float s3 = v.w * v.w; r8[b + 3] = r8[b + 3] + s3;
        }
        float h = ((r8[0] + r8[1]) + (r8[2] + r8[3]))
                + ((r8[4] + r8[5]) + (r8[6] + r8[7]));
        float ho = __shfl_down(h, 1, 64);    // odd lane's half-1 tree
        if (half == 0) rnormS[row] = h + ho; // fl(half0 + half1) — verified chain
    }

    STAGE_FX(&fXb[0][0], 0);
    __syncthreads();                     // drains DMA + x stage, publishes rnormS

    // Row norms (broadcast reads: 16 lanes share ty). row = 8*ty+r.
    float Arow[8];
    #pragma unroll
    for (int r = 0; r < 8; ++r) Arow[r] = rnormS[ty * 8 + r];

    float minv[8];
    int   mini[8];
    #pragma unroll
    for (int r = 0; r < 8; ++r) { minv[r] = 3.4e38f; mini[r] = 0; }

    float acc[8][16];
    // ---- Main: 64 steps, one barrier each. (R9 structure, unchanged.)
    #pragma unroll 2                     // compile-time buffer parity
    for (int s = 0; s < NSTEP; ++s) {
        const int p = s & 1;
        if (s < NSTEP - 1) {
            const int ns = s + 1;
            STAGE_DICT(&dTs[1 - p][0], ns >> 4, ns & 15);  // async, 0 regs
            STAGE_FX(&fXb[1 - p][0], ns & 15);             // regs die here
        }
        if ((s & 15) == 0) {
            #pragma unroll
            for (int r = 0; r < 8; ++r)
                #pragma unroll
                for (int j = 0; j < 16; ++j) acc[r][j] = 0.f;
        }
        #pragma unroll 4
        for (int dd = 0; dd < DC; ++dd) {
            // rows 8*ty..8*ty+7 at [dd][ty*8 .. ty*8+7] (pitch-4 packed)
            const float4 f0 = *(const float4*)&fXb[p][dd * FXW + ty * 8];
            const float4 f1 = *(const float4*)&fXb[p][dd * FXW + ty * 8 + 4];
            const float4 e0 = *(const float4*)&dTs[p][dd * BC + tx * 4];
            const float4 e1 = *(const float4*)&dTs[p][dd * BC + 64 + tx * 4];
            const float4 e2 = *(const float4*)&dTs[p][dd * BC + 128 + tx * 4];
            const float4 e3 = *(const float4*)&dTs[p][dd * BC + 192 + tx * 4];
            const float fr[8]  = {f0.x, f0.y, f0.z, f0.w, f1.x, f1.y, f1.z, f1.w};
            const float ec[16] = {e0.x, e0.y, e0.z, e0.w, e1.x, e1.y, e1.z, e1.w,
                                  e2.x, e2.y, e2.z, e2.w, e3.x, e3.y, e3.z, e3.w};
            #pragma unroll
            for (int r = 0; r < 8; ++r)
                #pragma unroll
                for (int j = 0; j < 16; ++j)
                    acc[r][j] = fmaf(fr[r], ec[j], acc[r][j]);
        }
        if ((s & 15) == 15) {
            // dist = fl( fl(A + B) - 2*s ) — np rounding chain (fma of
            // t1 - 2*acc bit-identical: 2*acc exact). Codes ascend with
            // (ct, j) for fixed tx -> strict < keeps FIRST min index.
            const int cbase = (s >> 4) * BC;
            float en[16];
            #pragma unroll
            for (int j = 0; j < 16; ++j)
                en[j] = enorm[cbase + (j >> 2) * 64 + tx * 4 + (j & 3)];
            #pragma unroll
            for (int r = 0; r < 8; ++r)
                #pragma unroll
                for (int j = 0; j < 16; ++j) {
                    int code = cbase + (j >> 2) * 64 + tx * 4 + (j & 3);
                    float t1 = Arow[r] + en[j];
                    float dist = t1 - 2.0f * acc[r][j];
                    if (dist < minv[r]) { minv[r] = dist; mini[r] = code; }
                }
        }
        __syncthreads();
    }

    // Cross-lane argmin over the 16 tx lanes (xor<16 stays in-wave; lane =
    // (ty&3)*16 + tx). Tie -> smaller index (first occurrence).
    #pragma unroll
    for (int m = 1; m < 16; m <<= 1)
        #pragma unroll
        for (int r = 0; r < 8; ++r) {
            float ov = __shfl_xor(minv[r], m, 64);
            int   oi = __shfl_xor(mini[r], m, 64);
            if (ov < minv[r] || (ov == minv[r] && oi < mini[r])) {
                minv[r] = ov; mini[r] = oi;
            }
        }

    int* idx_s = (int*)&dTs[0][0];       // loop-end barrier covers last compute
    if (tx == 0) {
        #pragma unroll
        for (int r = 0; r < 8; ++r) idx_s[ty * 8 + r] = mini[r];
    }
    __syncthreads();

    // Epilogue: gather codebook row (dictT L2-resident), re-read x (L3-hot),
    // emulate STE out = fl(x + fl(q-x)), loss on pure q (before STE).
    // unroll 2 = load ILP; lsum chain order preserved (no reassociation).
    // Nontemporal store: out is write-only, skip L2 RFO.
    float lsum = 0.f;
    {
#pragma clang fp contract(off)
        #pragma unroll 2
        for (int i = 0; i < BM; ++i) {
            int k = idx_s[i];
            float qv = dictT[(size_t)k * DDIM + tid];
            float xv = x[(size_t)(rowbase + i) * DDIM + tid];
            float diff = qv - xv;                                 // fl(q - x)
            __builtin_nontemporal_store(xv + diff,
                &out[(size_t)(rowbase + i) * DDIM + tid]);        // fl(x + fl(q-x))
            float d = xv - qv;
            float dsq = d * d;
            lsum = lsum + dsq;
        }
    }
    #pragma unroll
    for (int off = 32; off > 0; off >>= 1)
        lsum += __shfl_down(lsum, off, 64);
    if ((tid & 63) == 0)
        atomicAdd(loss, lsum * (1.25f / 16777216.0f));  // (1+BETA)/(N*D)
}

extern "C" void kernel_launch(void* const* d_in, const int* in_sizes, int n_in,
                              void* d_out, int out_size, void* d_ws, size_t ws_size,
                              hipStream_t stream) {
    (void)in_sizes; (void)n_in; (void)out_size; (void)ws_size;
    const float* x    = (const float*)d_in[0];
    const float* dict = (const float*)d_in[1];
    float* out   = (float*)d_out;
    float* enorm = (float*)d_ws;                 // 1024 floats
    float* dictT = enorm + KC;                   // 1024*256 floats (1 MB)
    float* loss  = out + (size_t)NROWS * DDIM;   // scalar slot after q

    vq_prep<<<KC / 64, 64, 0, stream>>>(dict, enorm, dictT, loss);
    vq_main<<<NROWS / BM, 256, 0, stream>>>(x, dict, enorm, dictT, out, loss);
}